// Round 1
// baseline (213.779 us; speedup 1.0000x reference)
//
#include <hip/hip_runtime.h>

// Ca_Aware_Embedder: distogram one-hot -> linear embed, fused.
// out[pair, c] = W[c, bin(pair)] + b[c], where bin() may be "none" -> b[c].
// Write-bandwidth-bound: 1024*1024*128 fp32 = 536.9 MB out.

constexpr int N_RES = 1024;
constexpr int C_Z = 128;
constexpr int NO_BINS = 15;
constexpr int PAIRS_PER_BLOCK = 8;   // 256 threads * float4 = 1024 floats = 8 pairs
constexpr float INF_UPPER = 100000000.0f;

__global__ __launch_bounds__(256) void ca_embedder_kernel(
    const float* __restrict__ x,   // [N_RES, 3]
    const float* __restrict__ W,   // [C_Z, NO_BINS]
    const float* __restrict__ b,   // [C_Z]
    float* __restrict__ out)       // [N_RES, N_RES, C_Z]
{
    __shared__ float Wt[NO_BINS + 1][C_Z];   // Wt[k][c] = W[c][k] + b[c]; row NO_BINS = b ("no bin")
    __shared__ int sbin[PAIRS_PER_BLOCK];

    // Stage W^T (+ b) into LDS
    for (int idx = threadIdx.x; idx < C_Z * NO_BINS; idx += 256) {
        int c = idx / NO_BINS;
        int k = idx - c * NO_BINS;
        Wt[k][c] = W[idx] + b[c];
    }
    if (threadIdx.x < C_Z) {
        Wt[NO_BINS][threadIdx.x] = b[threadIdx.x];
    }

    // Per-pair bin pre-pass (8 threads)
    if (threadIdx.x < PAIRS_PER_BLOCK) {
        int pair = blockIdx.x * PAIRS_PER_BLOCK + threadIdx.x;
        int i = pair >> 10;            // pair / N_RES
        int j = pair & (N_RES - 1);    // pair % N_RES
        float dx = x[3 * i + 0] - x[3 * j + 0];
        float dy = x[3 * i + 1] - x[3 * j + 1];
        float dz = x[3 * i + 2] - x[3 * j + 2];
        float d = dx * dx + dy * dy + dz * dz;

        int bin = NO_BINS;  // "no bin" -> b row
#pragma unroll
        for (int k = 0; k < NO_BINS; ++k) {
            float blo = 3.25f + 1.25f * (float)k;
            float lo = blo * blo;
            float bhi = 3.25f + 1.25f * (float)(k + 1);
            float hi = (k == NO_BINS - 1) ? INF_UPPER : bhi * bhi;
            if (d > lo && d < hi) bin = k;   // strict, matches reference
        }
        sbin[threadIdx.x] = bin;
    }
    __syncthreads();

    // Coalesced float4 writes: 32 threads per pair cover 128 channels
    int t = threadIdx.x;
    int lp = t >> 5;          // local pair 0..7
    int lane = t & 31;        // channel quad 0..31
    int bin = sbin[lp];
    float4 v = *reinterpret_cast<const float4*>(&Wt[bin][lane * 4]);
    size_t pair = (size_t)blockIdx.x * PAIRS_PER_BLOCK + lp;
    reinterpret_cast<float4*>(out)[pair * (C_Z / 4) + lane] = v;
}

extern "C" void kernel_launch(void* const* d_in, const int* in_sizes, int n_in,
                              void* d_out, int out_size, void* d_ws, size_t ws_size,
                              hipStream_t stream) {
    const float* x = (const float*)d_in[0];
    const float* W = (const float*)d_in[1];
    const float* b = (const float*)d_in[2];
    float* out = (float*)d_out;

    dim3 grid(N_RES * N_RES / PAIRS_PER_BLOCK);  // 131072 blocks
    ca_embedder_kernel<<<grid, 256, 0, stream>>>(x, W, b, out);
}

// Round 2
// 111.731 us; speedup vs baseline: 1.9133x; 1.9133x over previous
//
#include <hip/hip_runtime.h>

// Ca_Aware_Embedder: distogram one-hot -> linear embed, fused.
// out[pair, c] = W[c, bin(pair)] + b[c], where bin() may be "none" -> b[c].
// Write-bandwidth-bound: 1024*1024*128 fp32 = 536.9 MB out.
//
// R2: persistent grid (2048 blocks = 8/CU). Each block stages W^T+b into LDS
// ONCE, then streams 512 consecutive pairs (64 iters x 8 pairs) with no
// further barriers. Bin computed redundantly per 32-lane group in-register.

constexpr int N_RES = 1024;
constexpr int C_Z = 128;
constexpr int NO_BINS = 15;
constexpr int THREADS = 256;
constexpr int BLOCKS = 2048;                          // 8 blocks/CU on 256 CUs
constexpr int PAIRS_PER_ITER = THREADS / 32;          // 8 pairs per iteration
constexpr int PAIRS_PER_BLOCK = (N_RES * N_RES) / BLOCKS;  // 512 (= half a row)
constexpr int ITERS = PAIRS_PER_BLOCK / PAIRS_PER_ITER;    // 64
constexpr float INF_UPPER = 100000000.0f;

__global__ __launch_bounds__(THREADS) void ca_embedder_kernel(
    const float* __restrict__ x,   // [N_RES, 3]
    const float* __restrict__ W,   // [C_Z, NO_BINS]
    const float* __restrict__ b,   // [C_Z]
    float* __restrict__ out)       // [N_RES, N_RES, C_Z]
{
    __shared__ float Wt[NO_BINS + 1][C_Z];   // Wt[k][c] = W[c][k] + b[c]; row 15 = b ("no bin")

    // Stage W^T (+ b) into LDS once per block.
    for (int idx = threadIdx.x; idx < C_Z * NO_BINS; idx += THREADS) {
        int c = idx / NO_BINS;
        int k = idx - c * NO_BINS;
        Wt[k][c] = W[idx] + b[c];
    }
    if (threadIdx.x < C_Z) {
        Wt[NO_BINS][threadIdx.x] = b[threadIdx.x];
    }
    __syncthreads();

    const int lp = threadIdx.x >> 5;     // local pair within iteration, 0..7
    const int lane = threadIdx.x & 31;   // channel quad, 0..31

    const size_t base = (size_t)blockIdx.x * PAIRS_PER_BLOCK;
    // All 512 pairs of this block share the same row i (512 divides 1024).
    const int i = (int)(base >> 10);
    const float xi0 = x[3 * i + 0];
    const float xi1 = x[3 * i + 1];
    const float xi2 = x[3 * i + 2];
    const int j0 = (int)(base & (N_RES - 1));

    float4* __restrict__ out4 = reinterpret_cast<float4*>(out);

#pragma unroll 4
    for (int it = 0; it < ITERS; ++it) {
        const int j = j0 + it * PAIRS_PER_ITER + lp;
        const float dx = xi0 - x[3 * j + 0];
        const float dy = xi1 - x[3 * j + 1];
        const float dz = xi2 - x[3 * j + 2];
        const float d = dx * dx + dy * dy + dz * dz;

        int bin = NO_BINS;  // "no bin" -> b row
#pragma unroll
        for (int k = 0; k < NO_BINS; ++k) {
            const float blo = 3.25f + 1.25f * (float)k;
            const float lo = blo * blo;
            const float bhi = 3.25f + 1.25f * (float)(k + 1);
            const float hi = (k == NO_BINS - 1) ? INF_UPPER : bhi * bhi;
            if (d > lo && d < hi) bin = k;   // strict, matches reference
        }

        const float4 v = *reinterpret_cast<const float4*>(&Wt[bin][lane * 4]);
        const size_t pair = base + (size_t)(it * PAIRS_PER_ITER + lp);
        out4[pair * (C_Z / 4) + lane] = v;
    }
}

extern "C" void kernel_launch(void* const* d_in, const int* in_sizes, int n_in,
                              void* d_out, int out_size, void* d_ws, size_t ws_size,
                              hipStream_t stream) {
    const float* x = (const float*)d_in[0];
    const float* W = (const float*)d_in[1];
    const float* b = (const float*)d_in[2];
    float* out = (float*)d_out;

    ca_embedder_kernel<<<dim3(BLOCKS), dim3(THREADS), 0, stream>>>(x, W, b, out);
}

// Round 4
// 101.431 us; speedup vs baseline: 2.1076x; 1.1015x over previous
//
#include <hip/hip_runtime.h>

// Ca_Aware_Embedder: distogram one-hot -> linear embed, fused.
// out[pair, c] = W[c, bin(pair)] + b[c], where bin() may be "none" -> b[c].
// Write-bandwidth-bound: 1024*1024*128 fp32 = 536.9 MB out. Floor ~80 us at
// the fill-kernel's demonstrated 6.75 TB/s store rate.
//
// R4: same as R3 but with clang-native vector type for the nontemporal
// store (HIP's float4 class is rejected by __builtin_nontemporal_store).

typedef float f32x4 __attribute__((ext_vector_type(4)));

constexpr int N_RES = 1024;
constexpr int C_Z = 128;
constexpr int NO_BINS = 15;
constexpr int THREADS = 256;
constexpr int BLOCKS = 2048;                               // 8 blocks/CU
constexpr int PAIRS_PER_ITER = THREADS / 32;               // 8
constexpr int PAIRS_PER_BLOCK = (N_RES * N_RES) / BLOCKS;  // 512 (half a row)
constexpr int ITERS = PAIRS_PER_BLOCK / PAIRS_PER_ITER;    // 64
constexpr float INF_UPPER = 100000000.0f;

__global__ __launch_bounds__(THREADS) void ca_embedder_kernel(
    const float* __restrict__ x,   // [N_RES, 3]
    const float* __restrict__ W,   // [C_Z, NO_BINS]
    const float* __restrict__ b,   // [C_Z]
    float* __restrict__ out)       // [N_RES, N_RES, C_Z]
{
    __shared__ float Wt[NO_BINS + 1][C_Z];   // Wt[k][c] = W[c][k] + b[c]; row 15 = b
    __shared__ int sbin[PAIRS_PER_BLOCK];

    // Stage W^T (+ b) into LDS once per block.
    for (int idx = threadIdx.x; idx < C_Z * NO_BINS; idx += THREADS) {
        int c = idx / NO_BINS;
        int k = idx - c * NO_BINS;
        Wt[k][c] = W[idx] + b[c];
    }
    if (threadIdx.x < C_Z) {
        Wt[NO_BINS][threadIdx.x] = b[threadIdx.x];
    }

    const size_t base = (size_t)blockIdx.x * PAIRS_PER_BLOCK;
    // All 512 pairs of this block share row i (512 divides 1024).
    const int i = (int)(base >> 10);
    const float xi0 = x[3 * i + 0];
    const float xi1 = x[3 * i + 1];
    const float xi2 = x[3 * i + 2];
    const int j0 = (int)(base & (N_RES - 1));

    // Bin pre-pass: 512 bins, 2 per thread, exact reference semantics.
    for (int p = threadIdx.x; p < PAIRS_PER_BLOCK; p += THREADS) {
        const int j = j0 + p;
        const float dx = xi0 - x[3 * j + 0];
        const float dy = xi1 - x[3 * j + 1];
        const float dz = xi2 - x[3 * j + 2];
        const float d = dx * dx + dy * dy + dz * dz;

        int bin = NO_BINS;  // "no bin" -> b row
#pragma unroll
        for (int k = 0; k < NO_BINS; ++k) {
            const float blo = 3.25f + 1.25f * (float)k;
            const float lo = blo * blo;
            const float bhi = 3.25f + 1.25f * (float)(k + 1);
            const float hi = (k == NO_BINS - 1) ? INF_UPPER : bhi * bhi;
            if (d > lo && d < hi) bin = k;   // strict, matches reference
        }
        sbin[p] = bin;
    }
    __syncthreads();

    // Pure streaming loop: {bin broadcast read, Wt row read, nt store}.
    const int lp = threadIdx.x >> 5;     // local pair within iteration, 0..7
    const int lane = threadIdx.x & 31;   // channel quad, 0..31
    f32x4* __restrict__ out4 = reinterpret_cast<f32x4*>(out) + base * (C_Z / 4);

#pragma unroll 4
    for (int it = 0; it < ITERS; ++it) {
        const int p = it * PAIRS_PER_ITER + lp;
        const int bin = sbin[p];
        const f32x4 v = *reinterpret_cast<const f32x4*>(&Wt[bin][lane * 4]);
        __builtin_nontemporal_store(v, &out4[(size_t)p * (C_Z / 4) + lane]);
    }
}

extern "C" void kernel_launch(void* const* d_in, const int* in_sizes, int n_in,
                              void* d_out, int out_size, void* d_ws, size_t ws_size,
                              hipStream_t stream) {
    const float* x = (const float*)d_in[0];
    const float* W = (const float*)d_in[1];
    const float* b = (const float*)d_in[2];
    float* out = (float*)d_out;

    ca_embedder_kernel<<<dim3(BLOCKS), dim3(THREADS), 0, stream>>>(x, W, b, out);
}